// Round 7
// baseline (629.027 us; speedup 1.0000x reference)
//
#include <hip/hip_runtime.h>
#include <math.h>

#define NND 100000
#define NED 1600000
#define TDIM 768
#define VDIM 2048
#define ADIM 512
#define NVV 20000
#define NAA 20000
#define NBB 64
#define SUBROWS 8192   // budget for pruned layer-4 gather (sum over readout of deg+1)

#define NBLK_N ((NND + 255) / 256)
#define NBLK_E ((NED + 255) / 256)
#define NSCAN ((NND + 1023) / 1024)
#define NPACK 576            // 147456 pack elements / 256
// split-K input GEMM blocks: text 2Mx2K (32 rows), vision 1Mx4K (16 rows), audio 2Mx2K
#define NTB_TXT (NND / 32)   // 3125 (exact)
#define NTB_VIS (NVV / 16)   // 1250 (exact)
#define NTB_AUD (NAA / 32)   // 625 (exact)

// ---------------- bf16 helpers (RNE) ----------------
static __device__ __forceinline__ unsigned short f2bf(float f) {
  unsigned int u = __float_as_uint(f);
  unsigned int r = (u + 0x7fffu + ((u >> 16) & 1u)) >> 16;
  return (unsigned short)r;
}
static __device__ __forceinline__ float bf2f(unsigned int s) {
  return __uint_as_float(s << 16);
}

typedef __attribute__((ext_vector_type(8))) short bfrag;   // 8 bf16 = 4 VGPR
typedef __attribute__((ext_vector_type(4))) float facc4;   // MFMA accumulator

static __device__ __forceinline__ bfrag pack8(const float4& a, const float4& b) {
  union { bfrag v; unsigned short u[8]; } r;
  r.u[0] = f2bf(a.x); r.u[1] = f2bf(a.y); r.u[2] = f2bf(a.z); r.u[3] = f2bf(a.w);
  r.u[4] = f2bf(b.x); r.u[5] = f2bf(b.y); r.u[6] = f2bf(b.z); r.u[7] = f2bf(b.w);
  return r.v;
}

static __device__ __forceinline__ void unp8(uint4 u, float* x) {
  x[0] = bf2f(u.x & 0xffffu); x[1] = bf2f(u.x >> 16);
  x[2] = bf2f(u.y & 0xffffu); x[3] = bf2f(u.y >> 16);
  x[4] = bf2f(u.z & 0xffffu); x[5] = bf2f(u.z >> 16);
  x[6] = bf2f(u.w & 0xffffu); x[7] = bf2f(u.w >> 16);
}

// ---------------- wave reductions ----------------
static __device__ __forceinline__ float red16(float v) {
  #pragma unroll
  for (int m = 8; m >= 1; m >>= 1) v += __shfl_xor(v, m, 64);
  return v;  // sum within each 16-lane group
}
static __device__ __forceinline__ float red32(float v) {
  #pragma unroll
  for (int m = 16; m >= 1; m >>= 1) v += __shfl_xor(v, m, 64);
  return v;
}

// ---------------- init: cnt=1, fill=1, marks=0, cnts=0, scan aggs=0 ----------------
__global__ void k_init(int* cnt, int* fill, int* m3, int* m2, int* cnts, int* agg, int n) {
  int i = blockIdx.x * 256 + threadIdx.x;
  if (i < n) { cnt[i] = 1; fill[i] = 1; m3[i] = 0; m2[i] = 0; }
  if (i < 2) cnts[i] = 0;
  if (i < 128) agg[i] = 0;
}

// ---------------- degree count + weight pack (one launch) ----------------
__global__ void k_cntpack(
    const int* __restrict__ dst, int* cnt,
    const float* __restrict__ W0l, const float* __restrict__ W0r, unsigned short* o0,
    const float* __restrict__ W1l, const float* __restrict__ W1r, unsigned short* o1,
    const float* __restrict__ W2l, const float* __restrict__ W2r, unsigned short* o2,
    const float* __restrict__ W3l, const float* __restrict__ W3r, unsigned short* o3,
    const float* __restrict__ Wt, unsigned short* ot,
    const float* __restrict__ Wv, unsigned short* ov,
    const float* __restrict__ Wa, unsigned short* oa) {
  int bid = blockIdx.x;
  if (bid < NBLK_E) {
    int i = bid * 256 + threadIdx.x;
    if (i < NED) atomicAdd(&cnt[dst[i]], 1);
    return;
  }
  int i = (bid - NBLK_E) * 256 + threadIdx.x;
  if (i < 4096) { o0[i] = f2bf(W0l[i]); o0[4096 + i] = f2bf(W0r[i]); return; }
  i -= 4096;
  if (i < 16384) { o1[i] = f2bf(W1l[i]); o1[16384 + i] = f2bf(W1r[i]); return; }
  i -= 16384;
  if (i < 16384) { o2[i] = f2bf(W2l[i]); o2[16384 + i] = f2bf(W2r[i]); return; }
  i -= 16384;
  if (i < 4096) { o3[i] = f2bf(W3l[i]); o3[4096 + i] = f2bf(W3r[i]); return; }
  i -= 4096;
  if (i < 24576) { ot[i] = f2bf(Wt[i]); return; }
  i -= 24576;
  if (i < 65536) { ov[i] = f2bf(Wv[i]); return; }
  i -= 65536;
  if (i < 16384) { oa[i] = f2bf(Wa[i]); return; }
}

// ---------------- single-launch scan (decoupled lookback), writes rowptr ----------------
__global__ void k_scanall(const int* __restrict__ cnt, int* rp, int* agg, int n) {
  __shared__ int lds[256];
  int t = threadIdx.x, b = blockIdx.x;
  int base = b * 1024;
  int v[4];
  int s = 0;
  #pragma unroll
  for (int j = 0; j < 4; ++j) {
    int i = base + t * 4 + j;
    int c = (i < n) ? cnt[i] : 0;
    s += c; v[j] = s;
  }
  lds[t] = s;
  __syncthreads();
  for (int ofs = 1; ofs < 256; ofs <<= 1) {
    int x = (t >= ofs) ? lds[t - ofs] : 0;
    __syncthreads();
    lds[t] += x;
    __syncthreads();
  }
  int excl = (t > 0) ? lds[t - 1] : 0;
  int total = lds[255];
  if (t == 0) atomicExch(&agg[b], total);   // publish aggregate (total >= 1)
  __syncthreads();                          // done reading lds before reuse
  // parallel lookback over predecessors
  int psum = 0;
  for (int j = t; j < b; j += 256) {
    int a;
    do { a = atomicAdd(&agg[j], 0); } while (a == 0);
    psum += a;
  }
  lds[t] = psum;
  __syncthreads();
  for (int ofs = 128; ofs >= 1; ofs >>= 1) {
    if (t < ofs) lds[t] += lds[t + ofs];
    __syncthreads();
  }
  int prefix = lds[0];
  #pragma unroll
  for (int j = 0; j < 4; ++j) {
    int i = base + t * 4 + j;
    if (i < n) rp[i + 1] = prefix + excl + v[j];
  }
  if (b == 0 && t == 0) rp[0] = 0;
}

// ---------------- self-loop + edge fill (fill pre-initialized to 1) ----------------
__global__ void k_fill(const int* __restrict__ src, const int* __restrict__ dst,
                       const int* __restrict__ rp, int* fill, int* colidx, int n, int e) {
  int i = blockIdx.x * 256 + threadIdx.x;
  if (i < n) colidx[rp[i]] = i;                 // self-loop in slot 0
  if (i < e) {
    int d = dst[i];
    int p = atomicAdd(&fill[d], 1);             // p >= 1
    colidx[rp[d] + p] = src[i];
  }
}

// ---------------- layer-4 prep (block 0) + S3 mark (blocks 1..64) ----------------
__global__ void k_prep4m(const int* __restrict__ ptr, const int* __restrict__ rp,
                         const int* __restrict__ colidx, int* off, int* gidx, int* mark3) {
  if (blockIdx.x > 0) {
    int node = ptr[blockIdx.x - 1];
    int eb = rp[node], ee = rp[node + 1];
    if (threadIdx.x == 0) mark3[node] = 1;
    for (int e = eb + (int)threadIdx.x; e < ee; e += 256) mark3[colidx[e]] = 1;
    return;
  }
  __shared__ int cnt_s[64];
  __shared__ int off_s[65];
  int t = threadIdx.x;
  if (t < 64) {
    int node = ptr[t];
    int deg = rp[node + 1] - rp[node];
    if (deg > 126) deg = 126;  // safety clamp (SUBROWS budget)
    cnt_s[t] = deg + 1;        // +1: dst entry for xr
  }
  __syncthreads();
  if (t == 0) {
    int acc = 0;
    for (int i = 0; i < 64; ++i) { off_s[i] = acc; acc += cnt_s[i]; }
    off_s[64] = acc;
  }
  __syncthreads();
  if (t < 65) off[t] = off_s[t];
  if (t < 64) {
    int node = ptr[t];
    int o = off_s[t];
    gidx[o] = node;  // dst row (for xr)
    int eb = rp[node];
    int deg = cnt_s[t] - 1;
    for (int j = 0; j < deg; ++j) gidx[o + 1 + j] = colidx[eb + j];
  }
}

// ---------------- S2 mark: thread-per-node scan over mark3 ----------------
__global__ void k_mark2s(const int* __restrict__ mark3, const int* __restrict__ rp,
                         const int* __restrict__ colidx, int* mark2, int n) {
  int i = blockIdx.x * 256 + threadIdx.x;
  if (i >= n || !mark3[i]) return;
  mark2[i] = 1;
  int eb = rp[i], ee = rp[i + 1];
  for (int e = eb; e < ee; ++e) mark2[colidx[e]] = 1;
}

// ---------------- compact both frontiers in one launch ----------------
__global__ void k_compact2(const int* __restrict__ m3, const int* __restrict__ m2,
                           int* l3, int* l2, int* cnts, int n) {
  int i = blockIdx.x * 256 + threadIdx.x;
  if (i < n) {
    if (m3[i]) { int p = atomicAdd(&cnts[0], 1); l3[p] = i; }
    if (m2[i]) { int p = atomicAdd(&cnts[1], 1); l2[p] = i; }
  }
}

// ---------------- MFMA input GEMM body: C[M][32] = A[M][K] @ Wb^T + bias ----------------
// SPLIT-K: block = 4 waves = TILES M-tiles x KSPLIT K-chunks. Shorter per-wave load
// chains (vision x4 -> <=16 tiles/wave, matching text) -> better tail packing under
// latency-bound regime. Partials combined deterministically via LDS in fixed order
// (kh0 + kh1 [+ kh2 + kh3]), then bias + round.
template <int K, int KSPLIT, bool MEAN, bool OBF>
static __device__ __forceinline__ void gemm_in_body(
    const float* __restrict__ A, const unsigned short* __restrict__ Wb,
    const float* __restrict__ bias, void* __restrict__ Cv,
    float* __restrict__ rowmean, int bid, float* lred) {
  constexpr int TILES = 4 / KSPLIT;      // M-tiles per block
  constexpr int KH = K / KSPLIT;
  constexpr int KT2 = KH / 32;           // tiles per K-chunk: txt 12, vis 16, aud 8
  constexpr int NG = KT2 / 2;            // 2-tile groups: 6 / 8 / 4 (all even)
  static_assert(KT2 % 2 == 0 && NG % 2 == 0, "need even group count");
  const int wid = (int)threadIdx.x >> 6;
  const int lane = (int)threadIdx.x & 63;
  const int tile = wid % TILES;
  const int kh = wid / TILES;
  const int r16 = lane & 15;
  const int kg = lane >> 4;
  const int m0 = (bid * TILES + tile) * 16;   // M exact multiple of 16*TILES: no guards
  const float* arow = A + (size_t)(m0 + r16) * K + kh * KH + kg * 8;
  const unsigned short* w0 = Wb + (size_t)r16 * K + kh * KH + kg * 8;
  const unsigned short* w1 = Wb + (size_t)(16 + r16) * K + kh * KH + kg * 8;

  float4 A0[4], A1[4];
  bfrag W0[4], W1[4];
  facc4 acc0 = (facc4){0.f, 0.f, 0.f, 0.f};
  facc4 acc1 = (facc4){0.f, 0.f, 0.f, 0.f};
  float msum = 0.f;

  auto loadg = [&](float4* dA, bfrag* dW, int g) {
    #pragma unroll
    for (int t = 0; t < 2; ++t) {
      const float4* ap = reinterpret_cast<const float4*>(arow + (g * 2 + t) * 32);
      dA[2 * t] = ap[0];
      dA[2 * t + 1] = ap[1];
    }
    #pragma unroll
    for (int t = 0; t < 2; ++t) {
      dW[2 * t]     = *reinterpret_cast<const bfrag*>(w0 + (g * 2 + t) * 32);
      dW[2 * t + 1] = *reinterpret_cast<const bfrag*>(w1 + (g * 2 + t) * 32);
    }
  };
  auto consume = [&](const float4* sA, const bfrag* sW) {
    #pragma unroll
    for (int t = 0; t < 2; ++t) {
      float4 a0 = sA[2 * t], a1 = sA[2 * t + 1];
      if (MEAN) msum += (a0.x + a0.y + a0.z + a0.w) + (a1.x + a1.y + a1.z + a1.w);
      bfrag af = pack8(a0, a1);
      acc0 = __builtin_amdgcn_mfma_f32_16x16x32_bf16(af, sW[2 * t], acc0, 0, 0, 0);
      acc1 = __builtin_amdgcn_mfma_f32_16x16x32_bf16(af, sW[2 * t + 1], acc1, 0, 0, 0);
    }
  };

  loadg(A0, W0, 0);
  #pragma unroll 1
  for (int g = 0; g < NG; g += 2) {
    loadg(A1, W1, g + 1);
    __builtin_amdgcn_sched_barrier(0);
    consume(A0, W0);
    if (g + 2 < NG) loadg(A0, W0, g + 2);
    __builtin_amdgcn_sched_barrier(0);
    consume(A1, W1);
  }

  // cross-wave combine: kh>0 publish, kh=0 adds in fixed order (kh0+kh1[+kh2+kh3])
  if (kh > 0) {
    float* my = lred + (((kh - 1) * TILES + tile) * 64 + lane) * 9;
    #pragma unroll
    for (int r = 0; r < 4; ++r) { my[r] = acc0[r]; my[4 + r] = acc1[r]; }
    my[8] = msum;
  }
  __syncthreads();
  if (kh > 0) return;
  #pragma unroll
  for (int kk = 1; kk < KSPLIT; ++kk) {
    const float* src = lred + (((kk - 1) * TILES + tile) * 64 + lane) * 9;
    #pragma unroll
    for (int r = 0; r < 4; ++r) { acc0[r] += src[r]; acc1[r] += src[4 + r]; }
    if (MEAN) msum += src[8];
  }

  float b0v = bias[r16], b1v = bias[16 + r16];
  #pragma unroll
  for (int r = 0; r < 4; ++r) {
    int rowg = m0 + kg * 4 + r;
    float v0 = acc0[r] + b0v, v1 = acc1[r] + b1v;
    if (OBF) {
      unsigned short* C = (unsigned short*)Cv;
      C[(size_t)rowg * 32 + r16] = f2bf(v0);
      C[(size_t)rowg * 32 + 16 + r16] = f2bf(v1);
    } else {
      float* C = (float*)Cv;
      C[(size_t)rowg * 32 + r16] = v0;
      C[(size_t)rowg * 32 + 16 + r16] = v1;
    }
  }
  if (MEAN) {
    msum += __shfl_xor(msum, 16, 64);
    msum += __shfl_xor(msum, 32, 64);
    if (lane < 16) rowmean[m0 + r16] = msum * (1.f / (float)K);
  }
}

// all three input projections in one launch (concurrent, block-range dispatch)
__global__ __launch_bounds__(256) void k_gemm_in_all(
    const float* __restrict__ x, const unsigned short* __restrict__ wbt,
    const float* __restrict__ bt, unsigned short* fx, float* rowmean,
    const float* __restrict__ xv, const unsigned short* __restrict__ wbv,
    const float* __restrict__ bv, float* hvraw,
    const float* __restrict__ xa, const unsigned short* __restrict__ wba,
    const float* __restrict__ ba, float* haraw) {
  __shared__ float lred[3 * 64 * 9];   // max publishers: 3 (vision KSPLIT=4)
  int bid = blockIdx.x;
  if (bid < NTB_TXT) {
    gemm_in_body<TDIM, 2, true, true>(x, wbt, bt, fx, rowmean, bid, lred);
  } else if (bid < NTB_TXT + NTB_VIS) {
    gemm_in_body<VDIM, 4, false, false>(xv, wbv, bv, hvraw, nullptr, bid - NTB_TXT, lred);
  } else {
    gemm_in_body<ADIM, 2, false, false>(xa, wba, ba, haraw, nullptr, bid - NTB_TXT - NTB_VIS, lred);
  }
}

// ---------------- MFMA dual GEMM: [Cl|Cr] = A @ Wb^T + [bl|br] ----------------
// MODE 0: linear rows. MODE 1: gather A from rows[m], scatter C to rows[m].
// MODE 2: gather A from rows[m], write C linearly at m (layer-4 path).
template <int K, int NHALF, int WAVES, int MODE>
__global__ __launch_bounds__(WAVES * 64) void gemm_mfma(
    const unsigned short* __restrict__ A,
    const unsigned short* __restrict__ Wb,
    const float* __restrict__ bl, const float* __restrict__ br,
    unsigned short* __restrict__ Cl, unsigned short* __restrict__ Cr, int M,
    const int* __restrict__ rows, const int* __restrict__ rcnt) {
  constexpr int KT = K / 32;
  constexpr int NT = 2 * NHALF / 16;
  constexpr int NPW = NT / WAVES;
  static_assert(NPW >= 1, "bad wave split");
  const int wid = (int)threadIdx.x >> 6;
  const int lane = (int)threadIdx.x & 63;
  const int r16 = lane & 15;
  const int kg = lane >> 4;
  const int m0 = blockIdx.x * 16;
  int nr = M;
  if (MODE >= 1) nr = *rcnt;
  if (m0 >= nr) return;
  bfrag bf[NPW][KT];
  #pragma unroll
  for (int n = 0; n < NPW; ++n) {
    int col = (wid * NPW + n) * 16 + r16;
    #pragma unroll
    for (int kt = 0; kt < KT; ++kt)
      bf[n][kt] = *reinterpret_cast<const bfrag*>(Wb + (size_t)col * K + kt * 32 + kg * 8);
  }
  int ra = m0 + r16;
  if (MODE >= 1) { int mm = ra < nr ? ra : nr - 1; ra = rows[mm]; }
  bfrag af[KT];
  const unsigned short* arow = A + (size_t)ra * K + kg * 8;
  #pragma unroll
  for (int kt = 0; kt < KT; ++kt)
    af[kt] = *reinterpret_cast<const bfrag*>(arow + kt * 32);
  facc4 acc[NPW];
  #pragma unroll
  for (int n = 0; n < NPW; ++n) acc[n] = (facc4){0.f, 0.f, 0.f, 0.f};
  #pragma unroll
  for (int kt = 0; kt < KT; ++kt)
    #pragma unroll
    for (int n = 0; n < NPW; ++n)
      acc[n] = __builtin_amdgcn_mfma_f32_16x16x32_bf16(af[kt], bf[n][kt], acc[n], 0, 0, 0);
  #pragma unroll
  for (int n = 0; n < NPW; ++n) {
    int colg = (wid * NPW + n) * 16 + r16;
    bool isL = colg < NHALF;
    float bias = isL ? bl[colg] : br[colg - NHALF];
    #pragma unroll
    for (int r = 0; r < 4; ++r) {
      int m = m0 + kg * 4 + r;
      if (MODE == 1 && m >= nr) continue;
      int rowg = (MODE == 1) ? rows[m] : m;
      unsigned short v = f2bf(acc[n][r] + bias);
      if (isL) Cl[(size_t)rowg * NHALF + colg] = v;
      else     Cr[(size_t)rowg * NHALF + (colg - NHALF)] = v;
    }
  }
}

// ---- fused GATv2 agg + bias + (res) + LN + ELU, DIM=128, all-bf16 I/O ----
// 4 edges per wave: four 16-lane quarters, each lane owns 8 channels (uint4 = 16B
// gather per lane -> 256B coalesced per edge, 4x16B prefetch ring = 64B/lane in
// flight). Head (32ch) = 4 lanes; score reduce = 2 shuffles. Four quarter softmax
// states merged by two commutative online-merge stages (lane^16, lane^32).
// WL: process nodes from worklist wl[0..*wcnt) instead of 0..n.
template <bool RES, bool WL>
__global__ __launch_bounds__(256) void gat_agg_post128(
    const unsigned short* __restrict__ xl, const unsigned short* __restrict__ xr,
    const float* __restrict__ att,
    const int* __restrict__ rp, const int* __restrict__ colidx,
    const float* __restrict__ cb, const unsigned short* res,
    const float* __restrict__ g, const float* __restrict__ b,
    unsigned short* __restrict__ out, int n,
    const int* __restrict__ wl, const int* __restrict__ wcnt) {
  int wid = (blockIdx.x * 256 + threadIdx.x) >> 6;
  int node;
  if (WL) {
    if (wid >= *wcnt) return;
    node = wl[wid];
  } else {
    if (wid >= n) return;
    node = wid;
  }
  const int base = node * 128;
  int l = threadIdx.x & 63;
  const int lq = l & 15;          // lane within quarter
  const int q = l >> 4;           // quarter: processes edges q, q+4, q+8, ...
  const int c8 = 8 * lq;          // this lane's 8 channels (head = lq>>2)
  float av[8];
  {
    float4 aA = *reinterpret_cast<const float4*>(att + c8);
    float4 aB = *reinterpret_cast<const float4*>(att + c8 + 4);
    av[0] = aA.x; av[1] = aA.y; av[2] = aA.z; av[3] = aA.w;
    av[4] = aB.x; av[5] = aB.y; av[6] = aB.z; av[7] = aB.w;
  }
  float xr_[8];
  unp8(*reinterpret_cast<const uint4*>(xr + base + c8), xr_);
  float m_ = -1e30f, s_ = 0.f;
  float ac[8];
  #pragma unroll
  for (int i2 = 0; i2 < 8; ++i2) ac[i2] = 0.f;
  int eb = rp[node], ee = rp[node + 1];
  int cnt = ee - eb;              // >= 1 (self-loop)
  int nstep = (cnt + 3) >> 2;

  auto step = [&](uint4 cur, bool go) {
    float x[8];
    unp8(cur, x);
    float t = 0.f;
    #pragma unroll
    for (int i2 = 0; i2 < 8; ++i2) {
      float z = x[i2] + xr_[i2];
      t = fmaf((z > 0.f ? z : 0.2f * z), av[i2], t);
    }
    t += __shfl_xor(t, 1, 64);    // reduce over 4-lane head group
    t += __shfl_xor(t, 2, 64);
    if (!go) t = -1e30f;          // invalid: contributes w=0
    if (__any(t > m_ + 4.0f)) {   // rare rescale (defer-max), wave-uniform branch
      float nm = fmaxf(m_, t);
      float p = __expf(m_ - nm);
      float w = __expf(t - nm);
      s_ = s_ * p + w;
      #pragma unroll
      for (int i2 = 0; i2 < 8; ++i2) ac[i2] = ac[i2] * p + w * x[i2];
      m_ = nm;
    } else {
      float w = __expf(t - m_);
      s_ += w;
      #pragma unroll
      for (int i2 = 0; i2 < 8; ++i2) ac[i2] = fmaf(w, x[i2], ac[i2]);
    }
  };
  auto eclamp = [&](int s) { int e = 4 * s + q; return eb + (e < cnt ? e : cnt - 1); };
  auto ldx = [&](int sn) {
    return *reinterpret_cast<const uint4*>(xl + (size_t)sn * 128 + c8);
  };

  int idx[4];
  uint4 pv[4];
  #pragma unroll
  for (int k = 0; k < 4; ++k) idx[k] = colidx[eclamp(k)];
  #pragma unroll
  for (int k = 0; k < 4; ++k) pv[k] = ldx(idx[k]);
  for (int i = 0; i < nstep; i += 4) {
    uint4 qv[4];
    #pragma unroll
    for (int k = 0; k < 4; ++k) qv[k] = pv[k];
    if (i + 4 < nstep) {
      #pragma unroll
      for (int k = 0; k < 4; ++k) idx[k] = colidx[eclamp(i + 4 + k)];
      #pragma unroll
      for (int k = 0; k < 4; ++k) pv[k] = ldx(idx[k]);
    }
    step(qv[0], 4 * i + q < cnt);
    if (i + 1 < nstep) step(qv[1], 4 * (i + 1) + q < cnt);
    if (i + 2 < nstep) step(qv[2], 4 * (i + 2) + q < cnt);
    if (i + 3 < nstep) step(qv[3], 4 * (i + 3) + q < cnt);
  }

  // merge the 4 quarter softmax states: two pairwise online merges (lane^16, ^32).
  // Both partners compute a+b / b+a (commutative, bitwise equal) -> all replicas
  // identical. Empty quarter (m_=-1e30) contributes weight exp(-inf)=0.
  #pragma unroll
  for (int stage = 0; stage < 2; ++stage) {
    const int mask = (stage == 0) ? 16 : 32;
    float om = __shfl_xor(m_, mask, 64);
    float os = __shfl_xor(s_, mask, 64);
    float oa[8];
    #pragma unroll
    for (int i2 = 0; i2 < 8; ++i2) oa[i2] = __shfl_xor(ac[i2], mask, 64);
    float nm = fmaxf(m_, om);
    float ps = __expf(m_ - nm), po = __expf(om - nm);
    s_ = s_ * ps + os * po;
    #pragma unroll
    for (int i2 = 0; i2 < 8; ++i2) ac[i2] = ac[i2] * ps + oa[i2] * po;
    m_ = nm;
  }

  float inv = 1.f / (s_ + 1e-16f);
  float cbv[8];
  {
    float4 cA = *reinterpret_cast<const float4*>(cb + c8);
    float4 cB = *reinterpret_cast<const float4*>(cb + c8 + 4);
    cbv[0] = cA.x; cbv[1] = cA.y; cbv[2] = cA.z; cbv[3] = cA.w;
    cbv[4] = cB.x; cbv[5] = cB.y; cbv[6] = cB.z; cbv[7] = cB.w;
  }
  float v[8];
  #pragma unroll
  for (int i2 = 0; i2 < 8; ++i2) v[i2] = ac[i2] * inv + cbv[i2];
  if (RES) {
    float r[8];
    unp8(*reinterpret_cast<const uint4*>(res + base + c8), r);
    #pragma unroll
    for (int i2 = 0; i2 < 8; ++i2) v[i2] += r[i2];
  }
  float S = 0.f, Q = 0.f;
  #pragma unroll
  for (int i2 = 0; i2 < 8; ++i2) { S += v[i2]; Q += v[i2] * v[i2]; }
  #pragma unroll
  for (int m = 8; m >= 1; m >>= 1) {
    S += __shfl_xor(S, m, 64);
    Q += __shfl_xor(Q, m, 64);
  }
  float mean = S * (1.f / 128.f);
  float var = Q * (1.f / 128.f) - mean * mean;
  float rstd = rsqrtf(var + 1e-5f);
  float gv[8], bv[8];
  {
    float4 gA = *reinterpret_cast<const float4*>(g + c8);
    float4 gB = *reinterpret_cast<const float4*>(g + c8 + 4);
    float4 bA = *reinterpret_cast<const float4*>(b + c8);
    float4 bB = *reinterpret_cast<const float4*>(b + c8 + 4);
    gv[0] = gA.x; gv[1] = gA.y; gv[2] = gA.z; gv[3] = gA.w;
    gv[4] = gB.x; gv[5] = gB.y; gv[6] = gB.z; gv[7] = gB.w;
    bv[0] = bA.x; bv[1] = bA.y; bv[2] = bA.z; bv[3] = bA.w;
    bv[4] = bB.x; bv[5] = bB.y; bv[6] = bB.z; bv[7] = bB.w;
  }
  float y[8];
  #pragma unroll
  for (int i2 = 0; i2 < 8; ++i2) {
    float yy = (v[i2] - mean) * rstd * gv[i2] + bv[i2];
    y[i2] = (yy > 0.f) ? yy : expm1f(yy);
  }
  if (q == 0) {   // all quarters hold identical merged results; one stores
    uint4 o;
    o.x = (unsigned int)f2bf(y[0]) | ((unsigned int)f2bf(y[1]) << 16);
    o.y = (unsigned int)f2bf(y[2]) | ((unsigned int)f2bf(y[3]) << 16);
    o.z = (unsigned int)f2bf(y[4]) | ((unsigned int)f2bf(y[5]) << 16);
    o.w = (unsigned int)f2bf(y[6]) | ((unsigned int)f2bf(y[7]) << 16);
    *reinterpret_cast<uint4*>(out + base + c8) = o;
  }
}

// fused layer-4 agg + LN + Wo dot. 4 nodes/wave (16-lane groups), 64 nodes total.
__global__ __launch_bounds__(256) void k_agg4_final(
    const unsigned short* __restrict__ xls, const unsigned short* __restrict__ xrs,
    const float* __restrict__ att, const int* __restrict__ off,
    const float* __restrict__ cb, const float* __restrict__ g,
    const float* __restrict__ b, const float* __restrict__ Wo,
    const float* __restrict__ bo, float* __restrict__ out) {
  int wid = (blockIdx.x * 256 + threadIdx.x) >> 6;  // 0..15
  int l = threadIdx.x & 63;
  int lg = l & 15;
  int node = 4 * wid + (l >> 4);  // 0..63
  int c2 = 2 * lg;
  int p0 = off[node], pe = off[node + 1];
  int deg = pe - p0 - 1;  // >= 1 (self-loop)
  float2 a = *reinterpret_cast<const float2*>(att + c2);
  unsigned int xru = *reinterpret_cast<const unsigned int*>(xrs + (size_t)p0 * 32 + c2);
  float xr0 = bf2f(xru & 0xffffu), xr1 = bf2f(xru >> 16);
  float m_ = -1e30f, s_ = 0.f, accx = 0.f, accy = 0.f;
  for (int i = 0;; ++i) {
    bool go = i < deg;
    if (!__any(go)) break;
    float xcx = 0.f, xcy = 0.f;
    float t = -1e30f;
    if (go) {
      unsigned int pv = *reinterpret_cast<const unsigned int*>(xls + (size_t)(p0 + 1 + i) * 32 + c2);
      xcx = bf2f(pv & 0xffffu);
      xcy = bf2f(pv >> 16);
      float z0 = xcx + xr0, z1 = xcy + xr1;
      t = (z0 > 0.f ? z0 : 0.2f * z0) * a.x + (z1 > 0.f ? z1 : 0.2f * z1) * a.y;
    }
    t = red16(t);
    if (!go) t = -1e30f;
    if (__any(t > m_ + 4.0f)) {
      float nm = fmaxf(m_, t);
      float p = __expf(m_ - nm);
      float w = __expf(t - nm);
      s_ = s_ * p + w;
      accx = accx * p + w * xcx;
      accy = accy * p + w * xcy;
      m_ = nm;
    } else {
      float w = __expf(t - m_);
      s_ += w;
      accx = fmaf(w, xcx, accx);
      accy = fmaf(w, xcy, accy);
    }
  }
  float inv = 1.f / (s_ + 1e-16f);
  float2 cbv = *reinterpret_cast<const float2*>(cb + c2);
  float v0 = accx * inv + cbv.x;
  float v1 = accy * inv + cbv.y;
  float S = red16(v0 + v1);
  float Q = red16(v0 * v0 + v1 * v1);
  float mean = S * (1.f / 32.f);
  float var = Q * (1.f / 32.f) - mean * mean;
  float rstd = rsqrtf(var + 1e-5f);
  float2 gv = *reinterpret_cast<const float2*>(g + c2);
  float2 bv = *reinterpret_cast<const float2*>(b + c2);
  float y0 = (v0 - mean) * rstd * gv.x + bv.x;
  float y1 = (v1 - mean) * rstd * gv.y + bv.y;
  float2 wo = *reinterpret_cast<const float2*>(Wo + c2);
  float d = red16(y0 * wo.x + y1 * wo.y);
  if (lg == 0) out[node] = d + bo[0];
}

// ---------------- modal overwrite (vision+audio fused); fx is bf16 ----------------
__global__ __launch_bounds__(256) void k_modal2(
    unsigned short* fx, const float* __restrict__ hv, const float* __restrict__ ha,
    const int* __restrict__ vidx, const int* __restrict__ aidx,
    const float* __restrict__ gv, const float* __restrict__ bev,
    const float* __restrict__ ga, const float* __restrict__ bea,
    const float* __restrict__ rowmean, int nv, int na) {
  int wid = (blockIdx.x * 256 + threadIdx.x) >> 6;
  int l = threadIdx.x & 63;
  if (wid >= nv + na) return;
  bool isV = wid < nv;
  int w2 = isV ? wid : wid - nv;
  const float* hraw = isV ? hv : ha;
  const float* gg = isV ? gv : ga;
  const float* be = isV ? bev : bea;
  int node = isV ? vidx[w2] : aidx[w2];
  float mean = rowmean[node];
  float hval = (l < 32) ? hraw[(size_t)w2 * 32 + l] : 0.f;
  float S = red32(hval);
  float Q = red32(hval * hval);
  if (l < 32) {
    float m2 = S * (1.f / 32.f);
    float var = Q * (1.f / 32.f) - m2 * m2;
    float rstd = rsqrtf(var + 1e-5f);
    float y = (hval - m2) * rstd * gg[l] + be[l];
    y = fmaxf(y, 0.f);
    fx[(size_t)node * 32 + l] = f2bf(y * mean);
  }
}

// ---------------- host ----------------
extern "C" void kernel_launch(void* const* d_in, const int* in_sizes, int n_in,
                              void* d_out, int out_size, void* d_ws, size_t ws_size,
                              hipStream_t stream) {
  const float* x   = (const float*)d_in[0];
  const float* xv  = (const float*)d_in[1];
  const float* xa  = (const float*)d_in[2];
  const int* src   = (const int*)d_in[3];
  const int* dst   = (const int*)d_in[4];
  const int* vidx  = (const int*)d_in[5];
  const int* aidx  = (const int*)d_in[6];
  const int* ptr   = (const int*)d_in[7];
  const float* Wt  = (const float*)d_in[8];
  const float* bt  = (const float*)d_in[9];
  const float* Wv  = (const float*)d_in[10];
  const float* bv  = (const float*)d_in[11];
  const float* gv  = (const float*)d_in[12];
  const float* bev = (const float*)d_in[13];
  const float* Wa  = (const float*)d_in[14];
  const float* ba  = (const float*)d_in[15];
  const float* ga  = (const float*)d_in[16];
  const float* bea = (const float*)d_in[17];
  const float* cW_l[4], *cb_l[4], *cW_r[4], *cb_r[4], *c_att[4], *c_b[4];
  for (int i = 0; i < 4; ++i) {
    cW_l[i]  = (const float*)d_in[18 + 6 * i + 0];
    cb_l[i]  = (const float*)d_in[18 + 6 * i + 1];
    cW_r[i]  = (const float*)d_in[18 + 6 * i + 2];
    cb_r[i]  = (const float*)d_in[18 + 6 * i + 3];
    c_att[i] = (const float*)d_in[18 + 6 * i + 4];
    c_b[i]   = (const float*)d_in[18 + 6 * i + 5];
  }
  const float* ng[4], *nb_[4];
  for (int i = 0; i < 4; ++i) {
    ng[i]  = (const float*)d_in[42 + 2 * i + 0];
    nb_[i] = (const float*)d_in[42 + 2 * i + 1];
  }
  const float* Wo = (const float*)d_in[50];
  const float* bo = (const float*)d_in[51];
  float* out = (float*)d_out;

  char* w = (char*)d_ws;
  auto alloc = [&](size_t bytes) {
    char* p = w;
    w += (bytes + 255) & ~(size_t)255;
    return p;
  };
  int* rowptr = (int*)alloc((NND + 1) * sizeof(int));
  int* cnt    = (int*)alloc(NND * sizeof(int));
  int* aggs   = (int*)alloc(128 * sizeof(int));
  int* colidx = (int*)alloc((size_t)(NED + NND) * sizeof(int));
  float* rowmean = (float*)alloc((size_t)NND * sizeof(float));
  unsigned short* fx = (unsigned short*)alloc((size_t)NND * 32 * sizeof(unsigned short));
  unsigned short* h  = (unsigned short*)alloc((size_t)NND * 128 * sizeof(unsigned short));
  unsigned short* xlb = (unsigned short*)alloc((size_t)NND * 128 * sizeof(unsigned short));
  unsigned short* xrb = (unsigned short*)alloc((size_t)NND * 128 * sizeof(unsigned short));
  float* hvraw = (float*)alloc((size_t)NVV * 32 * sizeof(float));
  float* haraw = (float*)alloc((size_t)NAA * 32 * sizeof(float));
  unsigned short* wb0 = (unsigned short*)alloc(256 * 32 * sizeof(unsigned short));
  unsigned short* wb1 = (unsigned short*)alloc(256 * 128 * sizeof(unsigned short));
  unsigned short* wb2 = (unsigned short*)alloc(256 * 128 * sizeof(unsigned short));
  unsigned short* wb3 = (unsigned short*)alloc(64 * 128 * sizeof(unsigned short));
  unsigned short* wbt = (unsigned short*)alloc(32 * TDIM * sizeof(unsigned short));
  unsigned short* wbv = (unsigned short*)alloc(32 * VDIM * sizeof(unsigned short));
  unsigned short* wba = (unsigned short*)alloc(32 * ADIM * sizeof(unsigned short));
  int* off4 = (int*)alloc(65 * sizeof(int));
  int* gidx = (int*)alloc(SUBROWS * sizeof(int));
  unsigned short* xls = (unsigned short*)alloc((size_t)SUBROWS * 32 * sizeof(unsigned short));
  unsigned short* xrs = (unsigned short*)alloc((size_t)SUBROWS * 32 * sizeof(unsigned short));
  int* mark3 = (int*)alloc((size_t)NND * sizeof(int));
  int* mark2 = (int*)alloc((size_t)NND * sizeof(int));
  int* list3 = (int*)alloc((size_t)NND * sizeof(int));
  int* list2 = (int*)alloc((size_t)NND * sizeof(int));
  int* cnts  = (int*)alloc(2 * sizeof(int));

  const int nwave_n = (NND * 64 + 255) / 256;
  const int nwave_m2 = ((NVV + NAA) * 64 + 255) / 256;
  const int ntile = (NND + 15) / 16;      // 16-row MFMA tiles

  // fill (edge-fill cursor) reuses list2's space: list2 written only by k_compact2,
  // which runs after k_fill completes.
  int* fill = list2;
  k_init<<<NBLK_N, 256, 0, stream>>>(cnt, fill, mark3, mark2, cnts, aggs, NND);
  // degree count + weight pack
  k_cntpack<<<NBLK_E + NPACK, 256, 0, stream>>>(
      dst, cnt,
      cW_l[0], cW_r[0], wb0, cW_l[1], cW_r[1], wb1,
      cW_l[2], cW_r[2], wb2, cW_l[3], cW_r[3], wb3,
      Wt, wbt, Wv, wbv, Wa, wba);
  // single-launch scan -> rowptr
  k_scanall<<<NSCAN, 256, 0, stream>>>(cnt, rowptr, aggs, NND);
  // self-loop + edge fill
  k_fill<<<NBLK_E, 256, 0, stream>>>(src, dst, rowptr, fill, colidx, NND, NED);
  // layer-4 prep + S3 mark
  k_prep4m<<<65, 256, 0, stream>>>(ptr, rowptr, colidx, off4, gidx, mark3);
  // S2 mark
  k_mark2s<<<NBLK_N, 256, 0, stream>>>(mark3, rowptr, colidx, mark2, NND);
  // compact both frontiers
  k_compact2<<<NBLK_N, 256, 0, stream>>>(mark3, mark2, list3, list2, cnts, NND);
  // all input projections (text 2x2 split-K, vision 1x4, audio 2x2)
  k_gemm_in_all<<<NTB_TXT + NTB_VIS + NTB_AUD, 256, 0, stream>>>(
      x, wbt, bt, fx, rowmean, xv, wbv, bv, hvraw, xa, wba, ba, haraw);
  // modal overwrite
  k_modal2<<<nwave_m2, 256, 0, stream>>>(
      fx, hvraw, haraw, vidx, aidx, gv, bev, ga, bea, rowmean, NVV, NAA);

  // layer 1 (full): fx(32) -> h(128)
  gemm_mfma<32, 128, 8, 0><<<ntile, 512, 0, stream>>>(
      fx, wb0, cb_l[0], cb_r[0], xlb, xrb, NND, nullptr, nullptr);
  gat_agg_post128<false, false><<<nwave_n, 256, 0, stream>>>(
      xlb, xrb, c_att[0], rowptr, colidx, c_b[0], nullptr, ng[0], nb_[0], h, NND,
      nullptr, nullptr);

  // layer 2: full projection (xl needed at N(S2) ~ all), agg only at S2
  gemm_mfma<128, 128, 8, 0><<<ntile, 512, 0, stream>>>(
      h, wb1, cb_l[1], cb_r[1], xlb, xrb, NND, nullptr, nullptr);
  gat_agg_post128<true, true><<<nwave_n, 256, 0, stream>>>(
      xlb, xrb, c_att[1], rowptr, colidx, c_b[1], h, ng[1], nb_[1], h, NND,
      list2, cnts + 1);

  // layer 3: projection only at S2 rows (gather/scatter), agg only at S3
  gemm_mfma<128, 128, 8, 1><<<ntile, 512, 0, stream>>>(
      h, wb2, cb_l[2], cb_r[2], xlb, xrb, NND, list2, cnts + 1);
  gat_agg_post128<true, true><<<4096, 256, 0, stream>>>(   // 16384 waves >= |S3|
      xlb, xrb, c_att[2], rowptr, colidx, c_b[2], h, ng[2], nb_[2], h, NND,
      list3, cnts + 0);

  // layer-4 projection: gather h rows via gidx, write xls/xrs linearly
  gemm_mfma<128, 32, 4, 2><<<SUBROWS / 16, 256, 0, stream>>>(
      h, wb3, cb_l[3], cb_r[3], xls, xrs, SUBROWS, gidx, off4 + 64);
  // final agg + LN + Wo
  k_agg4_final<<<4, 256, 0, stream>>>(
      xls, xrs, c_att[3], off4, c_b[3], ng[3], nb_[3], Wo, bo, out);
}

// Round 8
// 582.535 us; speedup vs baseline: 1.0798x; 1.0798x over previous
//
#include <hip/hip_runtime.h>
#include <math.h>

#define NND 100000
#define NED 1600000
#define TDIM 768
#define VDIM 2048
#define ADIM 512
#define NVV 20000
#define NAA 20000
#define NBB 64
#define SUBROWS 8192   // budget for pruned layer-4 gather (sum over readout of deg+1)

#define NBLK_N ((NND + 255) / 256)        // 391
#define NBLK_E ((NED + 255) / 256)        // 6250
#define NBLK_E512 ((NED + 511) / 512)     // 3125
#define NM512 ((NND + 511) / 512)         // 196
#define NSCAN ((NND + 1023) / 1024)       // 98
#define NPACK 576                          // 147456 pack elements / 256
#define NTILE ((NND + 15) / 16)           // 6250  (16-row MFMA tiles)
#define NWAVEN ((NND * 64 + 255) / 256)   // 25000 (1 wave per node)
#define NWAVEM2 (((NVV + NAA) * 64 + 255) / 256) // 10000
// split-K x2 input GEMM: each block = 2 M-tiles x 2 K-halves (32 rows/block)
#define NTB_TXT (NND / 32)   // 3125 (exact)
#define NTB_VIS (NVV / 32)   // 625 (exact)
#define NTB_AUD (NAA / 32)   // 625 (exact)

// ---------------- bf16 helpers (RNE) ----------------
static __device__ __forceinline__ unsigned short f2bf(float f) {
  unsigned int u = __float_as_uint(f);
  unsigned int r = (u + 0x7fffu + ((u >> 16) & 1u)) >> 16;
  return (unsigned short)r;
}
static __device__ __forceinline__ float bf2f(unsigned int s) {
  return __uint_as_float(s << 16);
}

typedef __attribute__((ext_vector_type(8))) short bfrag;   // 8 bf16 = 4 VGPR
typedef __attribute__((ext_vector_type(4))) float facc4;   // MFMA accumulator

static __device__ __forceinline__ bfrag pack8(const float4& a, const float4& b) {
  union { bfrag v; unsigned short u[8]; } r;
  r.u[0] = f2bf(a.x); r.u[1] = f2bf(a.y); r.u[2] = f2bf(a.z); r.u[3] = f2bf(a.w);
  r.u[4] = f2bf(b.x); r.u[5] = f2bf(b.y); r.u[6] = f2bf(b.z); r.u[7] = f2bf(b.w);
  return r.v;
}

// ---------------- wave reductions ----------------
static __device__ __forceinline__ float red16(float v) {
  #pragma unroll
  for (int m = 8; m >= 1; m >>= 1) v += __shfl_xor(v, m, 64);
  return v;  // sum within each 16-lane group
}
static __device__ __forceinline__ float red32(float v) {
  #pragma unroll
  for (int m = 16; m >= 1; m >>= 1) v += __shfl_xor(v, m, 64);
  return v;
}

// ================== device bodies (shared by fused + standalone kernels) ==================

// ---- weight pack body (index i in [0, 147456)) ----
static __device__ __forceinline__ void pack_body(
    int i,
    const float* __restrict__ W0l, const float* __restrict__ W0r, unsigned short* o0,
    const float* __restrict__ W1l, const float* __restrict__ W1r, unsigned short* o1,
    const float* __restrict__ W2l, const float* __restrict__ W2r, unsigned short* o2,
    const float* __restrict__ W3l, const float* __restrict__ W3r, unsigned short* o3,
    const float* __restrict__ Wt, unsigned short* ot,
    const float* __restrict__ Wv, unsigned short* ov,
    const float* __restrict__ Wa, unsigned short* oa) {
  if (i < 4096) { o0[i] = f2bf(W0l[i]); o0[4096 + i] = f2bf(W0r[i]); return; }
  i -= 4096;
  if (i < 16384) { o1[i] = f2bf(W1l[i]); o1[16384 + i] = f2bf(W1r[i]); return; }
  i -= 16384;
  if (i < 16384) { o2[i] = f2bf(W2l[i]); o2[16384 + i] = f2bf(W2r[i]); return; }
  i -= 16384;
  if (i < 4096) { o3[i] = f2bf(W3l[i]); o3[4096 + i] = f2bf(W3r[i]); return; }
  i -= 4096;
  if (i < 24576) { ot[i] = f2bf(Wt[i]); return; }
  i -= 24576;
  if (i < 65536) { ov[i] = f2bf(Wv[i]); return; }
  i -= 65536;
  if (i < 16384) { oa[i] = f2bf(Wa[i]); return; }
}

// ---- single-launch scan body (decoupled lookback); lds = 256 ints ----
static __device__ __forceinline__ void scan_body(
    const int* __restrict__ cnt, int* rp, int* agg, int n, int b, int* lds) {
  int t = threadIdx.x;
  int base = b * 1024;
  int v[4];
  int s = 0;
  #pragma unroll
  for (int j = 0; j < 4; ++j) {
    int i = base + t * 4 + j;
    int c = (i < n) ? cnt[i] : 0;
    s += c; v[j] = s;
  }
  lds[t] = s;
  __syncthreads();
  for (int ofs = 1; ofs < 256; ofs <<= 1) {
    int x = (t >= ofs) ? lds[t - ofs] : 0;
    __syncthreads();
    lds[t] += x;
    __syncthreads();
  }
  int excl = (t > 0) ? lds[t - 1] : 0;
  int total = lds[255];
  if (t == 0) atomicExch(&agg[b], total);   // publish aggregate (total >= 1)
  __syncthreads();                          // done reading lds before reuse
  // parallel lookback over predecessors
  int psum = 0;
  for (int j = t; j < b; j += 256) {
    int a;
    do { a = atomicAdd(&agg[j], 0); } while (a == 0);
    psum += a;
  }
  lds[t] = psum;
  __syncthreads();
  for (int ofs = 128; ofs >= 1; ofs >>= 1) {
    if (t < ofs) lds[t] += lds[t + ofs];
    __syncthreads();
  }
  int prefix = lds[0];
  #pragma unroll
  for (int j = 0; j < 4; ++j) {
    int i = base + t * 4 + j;
    if (i < n) rp[i + 1] = prefix + excl + v[j];
  }
  if (b == 0 && t == 0) rp[0] = 0;
}

// ---- modal overwrite body (vision+audio); fx is bf16 ----
static __device__ __forceinline__ void modal_body(
    unsigned short* fx, const float* __restrict__ hv, const float* __restrict__ ha,
    const int* __restrict__ vidx, const int* __restrict__ aidx,
    const float* __restrict__ gv, const float* __restrict__ bev,
    const float* __restrict__ ga, const float* __restrict__ bea,
    const float* __restrict__ rowmean, int nv, int na, int bid) {
  int wid = bid * 4 + ((int)threadIdx.x >> 6);
  int l = threadIdx.x & 63;
  if (wid >= nv + na) return;
  bool isV = wid < nv;
  int w2 = isV ? wid : wid - nv;
  const float* hraw = isV ? hv : ha;
  const float* gg = isV ? gv : ga;
  const float* be = isV ? bev : bea;
  int node = isV ? vidx[w2] : aidx[w2];
  float mean = rowmean[node];
  float hval = (l < 32) ? hraw[(size_t)w2 * 32 + l] : 0.f;
  float S = red32(hval);
  float Q = red32(hval * hval);
  if (l < 32) {
    float m2 = S * (1.f / 32.f);
    float var = Q * (1.f / 32.f) - m2 * m2;
    float rstd = rsqrtf(var + 1e-5f);
    float y = (hval - m2) * rstd * gg[l] + be[l];
    y = fmaxf(y, 0.f);
    fx[(size_t)node * 32 + l] = f2bf(y * mean);
  }
}

// ---- layer-4 prep body: bid 0 = offsets+gather ids; bid 1..64 = S3 mark ----
static __device__ __forceinline__ void prep4_body(
    const int* __restrict__ ptr, const int* __restrict__ rp,
    const int* __restrict__ colidx, int* off, int* gidx, int* mark3,
    int bid, int* cnt_s, int* off_s) {
  if (bid > 0) {
    int node = ptr[bid - 1];
    int eb = rp[node], ee = rp[node + 1];
    if (threadIdx.x == 0) mark3[node] = 1;
    for (int e = eb + (int)threadIdx.x; e < ee; e += 256) mark3[colidx[e]] = 1;
    return;
  }
  int t = threadIdx.x;
  if (t < 64) {
    int node = ptr[t];
    int deg = rp[node + 1] - rp[node];
    if (deg > 126) deg = 126;  // safety clamp (SUBROWS budget)
    cnt_s[t] = deg + 1;        // +1: dst entry for xr
  }
  __syncthreads();
  if (t == 0) {
    int acc = 0;
    for (int i = 0; i < 64; ++i) { off_s[i] = acc; acc += cnt_s[i]; }
    off_s[64] = acc;
  }
  __syncthreads();
  if (t < 65) off[t] = off_s[t];
  if (t < 64) {
    int node = ptr[t];
    int o = off_s[t];
    gidx[o] = node;  // dst row (for xr)
    int eb = rp[node];
    int deg = cnt_s[t] - 1;
    for (int j = 0; j < deg; ++j) gidx[o + 1 + j] = colidx[eb + j];
  }
}

// ---- MFMA input GEMM body: C[M][32] = A[M][K] @ Wb^T + bias, SPLIT-K x2 ----
// block = 4 waves = 2 M-tiles x 2 K-halves. Partials combined deterministically
// via LDS in fixed order (kh0 + kh1), then bias + round. (R6 version.)
template <int K, bool MEAN, bool OBF>
static __device__ __forceinline__ void gemm_in_body(
    const float* __restrict__ A, const unsigned short* __restrict__ Wb,
    const float* __restrict__ bias, void* __restrict__ Cv,
    float* __restrict__ rowmean, int bid, float* lred) {
  constexpr int KH = K / 2;
  constexpr int KT2 = KH / 32;           // tiles per K-half: 12 / 32 / 8
  constexpr int NG = KT2 / 2;            // 2-tile groups: 6 / 16 / 4 (all even)
  static_assert(KT2 % 2 == 0 && NG % 2 == 0, "need even group count");
  const int wid = (int)threadIdx.x >> 6;
  const int lane = (int)threadIdx.x & 63;
  const int tile = wid & 1;
  const int kh = wid >> 1;
  const int r16 = lane & 15;
  const int kg = lane >> 4;
  const int m0 = (bid * 2 + tile) * 16;  // M is an exact multiple of 32: no guards
  const float* arow = A + (size_t)(m0 + r16) * K + kh * KH + kg * 8;
  const unsigned short* w0 = Wb + (size_t)r16 * K + kh * KH + kg * 8;
  const unsigned short* w1 = Wb + (size_t)(16 + r16) * K + kh * KH + kg * 8;

  float4 A0[4], A1[4];
  bfrag W0[4], W1[4];
  facc4 acc0 = (facc4){0.f, 0.f, 0.f, 0.f};
  facc4 acc1 = (facc4){0.f, 0.f, 0.f, 0.f};
  float msum = 0.f;

  auto loadg = [&](float4* dA, bfrag* dW, int g) {
    #pragma unroll
    for (int t = 0; t < 2; ++t) {
      const float4* ap = reinterpret_cast<const float4*>(arow + (g * 2 + t) * 32);
      dA[2 * t] = ap[0];
      dA[2 * t + 1] = ap[1];
    }
    #pragma unroll
    for (int t = 0; t < 2; ++t) {
      dW[2 * t]     = *reinterpret_cast<const bfrag*>(w0 + (g * 2 + t) * 32);
      dW[2 * t + 1] = *reinterpret_cast<const bfrag*>(w1 + (g * 2 + t) * 32);
    }
  };
  auto consume = [&](const float4* sA, const bfrag* sW) {
    #pragma unroll
    for (int t = 0; t < 2; ++t) {
      float4 a0 = sA[2 * t], a1 = sA[2 * t + 1];
      if (MEAN) msum += (a0.x + a0.y + a0.z + a0.w) + (a1.x + a1.y + a1.z + a1.w);
      bfrag af = pack8(a0, a1);
      acc0 = __builtin_amdgcn_mfma_f32_16x16x32_bf16(af, sW[2 * t], acc0, 0, 0, 0);
      acc1 = __builtin_amdgcn_mfma_f32_16x16x32_bf16(af, sW[2 * t + 1], acc1, 0, 0, 0);
    }
  };

  loadg(A0, W0, 0);
  #pragma unroll 1
  for (int g = 0; g < NG; g += 2) {
    loadg(A1, W1, g + 1);                 // g+1 <= NG-1 always (NG even)
    __builtin_amdgcn_sched_barrier(0);
    consume(A0, W0);
    if (g + 2 < NG) loadg(A0, W0, g + 2);
    __builtin_amdgcn_sched_barrier(0);
    consume(A1, W1);
  }

  // cross-wave combine: kh=1 publishes, kh=0 adds in fixed order (kh0 + kh1)
  float* my = lred + ((size_t)tile * 64 + lane) * 9;
  if (kh == 1) {
    #pragma unroll
    for (int r = 0; r < 4; ++r) { my[r] = acc0[r]; my[4 + r] = acc1[r]; }
    my[8] = msum;
  }
  __syncthreads();
  if (kh == 1) return;
  #pragma unroll
  for (int r = 0; r < 4; ++r) { acc0[r] += my[r]; acc1[r] += my[4 + r]; }
  if (MEAN) msum += my[8];

  float b0v = bias[r16], b1v = bias[16 + r16];
  #pragma unroll
  for (int r = 0; r < 4; ++r) {
    int rowg = m0 + kg * 4 + r;
    float v0 = acc0[r] + b0v, v1 = acc1[r] + b1v;
    if (OBF) {
      unsigned short* C = (unsigned short*)Cv;
      C[(size_t)rowg * 32 + r16] = f2bf(v0);
      C[(size_t)rowg * 32 + 16 + r16] = f2bf(v1);
    } else {
      float* C = (float*)Cv;
      C[(size_t)rowg * 32 + r16] = v0;
      C[(size_t)rowg * 32 + 16 + r16] = v1;
    }
  }
  if (MEAN) {
    msum += __shfl_xor(msum, 16, 64);
    msum += __shfl_xor(msum, 32, 64);
    if (lane < 16) rowmean[m0 + r16] = msum * (1.f / (float)K);
  }
}

// ---- MFMA dual GEMM body: [Cl|Cr] = A @ Wb^T + [bl|br] ----
// MODE 0: linear rows. MODE 1: gather A from rows[m], scatter C to rows[m].
// MODE 2: gather A from rows[m], write C linearly at m (layer-4 path).
template <int K, int NHALF, int WAVES, int MODE>
static __device__ __forceinline__ void gemm_body(
    const unsigned short* __restrict__ A,
    const unsigned short* __restrict__ Wb,
    const float* __restrict__ bl, const float* __restrict__ br,
    unsigned short* __restrict__ Cl, unsigned short* __restrict__ Cr, int M,
    const int* __restrict__ rows, const int* __restrict__ rcnt, int bid) {
  constexpr int KT = K / 32;
  constexpr int NT = 2 * NHALF / 16;
  constexpr int NPW = NT / WAVES;
  static_assert(NPW >= 1, "bad wave split");
  const int wid = (int)threadIdx.x >> 6;
  const int lane = (int)threadIdx.x & 63;
  const int r16 = lane & 15;
  const int kg = lane >> 4;
  const int m0 = bid * 16;
  int nr = M;
  if (MODE >= 1) nr = *rcnt;
  if (m0 >= nr) return;
  bfrag bf[NPW][KT];
  #pragma unroll
  for (int n = 0; n < NPW; ++n) {
    int col = (wid * NPW + n) * 16 + r16;
    #pragma unroll
    for (int kt = 0; kt < KT; ++kt)
      bf[n][kt] = *reinterpret_cast<const bfrag*>(Wb + (size_t)col * K + kt * 32 + kg * 8);
  }
  int ra = m0 + r16;
  if (MODE >= 1) { int mm = ra < nr ? ra : nr - 1; ra = rows[mm]; }
  bfrag af[KT];
  const unsigned short* arow = A + (size_t)ra * K + kg * 8;
  #pragma unroll
  for (int kt = 0; kt < KT; ++kt)
    af[kt] = *reinterpret_cast<const bfrag*>(arow + kt * 32);
  facc4 acc[NPW];
  #pragma unroll
  for (int n = 0; n < NPW; ++n) acc[n] = (facc4){0.f, 0.f, 0.f, 0.f};
  #pragma unroll
  for (int kt = 0; kt < KT; ++kt)
    #pragma unroll
    for (int n = 0; n < NPW; ++n)
      acc[n] = __builtin_amdgcn_mfma_f32_16x16x32_bf16(af[kt], bf[n][kt], acc[n], 0, 0, 0);
  #pragma unroll
  for (int n = 0; n < NPW; ++n) {
    int colg = (wid * NPW + n) * 16 + r16;
    bool isL = colg < NHALF;
    float bias = isL ? bl[colg] : br[colg - NHALF];
    #pragma unroll
    for (int r = 0; r < 4; ++r) {
      int m = m0 + kg * 4 + r;
      if (MODE == 1 && m >= nr) continue;
      int rowg = (MODE == 1) ? rows[m] : m;
      unsigned short v = f2bf(acc[n][r] + bias);
      if (isL) Cl[(size_t)rowg * NHALF + colg] = v;
      else     Cr[(size_t)rowg * NHALF + (colg - NHALF)] = v;
    }
  }
}

// ---- fused GATv2 agg + bias + (res) + LN + ELU body, DIM=128 (R6 2-edge version) ----
// 2 edges per wave: lanes 0-31 even edges, lanes 32-63 odd edges; each lane owns
// 4 channels. Half-wave softmax states merged at lane^32.
template <bool RES, bool WL>
static __device__ __forceinline__ void agg_body(
    const unsigned short* __restrict__ xl, const unsigned short* __restrict__ xr,
    const float* __restrict__ att,
    const int* __restrict__ rp, const int* __restrict__ colidx,
    const float* __restrict__ cb, const unsigned short* res,
    const float* __restrict__ g, const float* __restrict__ b,
    unsigned short* __restrict__ out, int n,
    const int* __restrict__ wl, const int* __restrict__ wcnt, int bid) {
  int wid = bid * 4 + ((int)threadIdx.x >> 6);
  int node;
  if (WL) {
    if (wid >= *wcnt) return;
    node = wl[wid];
  } else {
    if (wid >= n) return;
    node = wid;
  }
  const int base = node * 128;
  int l = threadIdx.x & 63;
  const int lh = l & 31;          // lane within half-wave
  const int half = l >> 5;        // 0: even edges, 1: odd edges
  const int c4 = 4 * lh;          // this lane's 4 channels (head = lh>>3)
  float4 a = *reinterpret_cast<const float4*>(att + c4);
  uint2 xru = *reinterpret_cast<const uint2*>(xr + base + c4);
  float xr0 = bf2f(xru.x & 0xffffu), xr1 = bf2f(xru.x >> 16);
  float xr2 = bf2f(xru.y & 0xffffu), xr3 = bf2f(xru.y >> 16);
  float m_ = -1e30f, s_ = 0.f;
  float ac0 = 0.f, ac1 = 0.f, ac2 = 0.f, ac3 = 0.f;
  int eb = rp[node], ee = rp[node + 1];
  int cnt = ee - eb;              // >= 1 (self-loop)
  int nstep = (cnt + 1) >> 1;

  auto step = [&](uint2 cur, bool go) {
    float x0 = bf2f(cur.x & 0xffffu), x1 = bf2f(cur.x >> 16);
    float x2 = bf2f(cur.y & 0xffffu), x3 = bf2f(cur.y >> 16);
    float z0 = x0 + xr0, z1 = x1 + xr1, z2 = x2 + xr2, z3 = x3 + xr3;
    float t = (z0 > 0.f ? z0 : 0.2f * z0) * a.x + (z1 > 0.f ? z1 : 0.2f * z1) * a.y
            + (z2 > 0.f ? z2 : 0.2f * z2) * a.z + (z3 > 0.f ? z3 : 0.2f * z3) * a.w;
    t += __shfl_xor(t, 1, 64);    // reduce over 8-lane head group
    t += __shfl_xor(t, 2, 64);
    t += __shfl_xor(t, 4, 64);
    if (!go) t = -1e30f;          // invalid (odd tail): contributes w=0
    if (__any(t > m_ + 4.0f)) {   // rare rescale (defer-max), wave-uniform branch
      float nm = fmaxf(m_, t);
      float p = __expf(m_ - nm);
      float w = __expf(t - nm);
      s_ = s_ * p + w;
      ac0 = ac0 * p + w * x0; ac1 = ac1 * p + w * x1;
      ac2 = ac2 * p + w * x2; ac3 = ac3 * p + w * x3;
      m_ = nm;
    } else {
      float w = __expf(t - m_);
      s_ += w;
      ac0 = fmaf(w, x0, ac0); ac1 = fmaf(w, x1, ac1);
      ac2 = fmaf(w, x2, ac2); ac3 = fmaf(w, x3, ac3);
    }
  };
  auto eclamp = [&](int s) { int e = 2 * s + half; return eb + (e < cnt ? e : cnt - 1); };
  auto ldx = [&](int sn) {
    return *reinterpret_cast<const uint2*>(xl + (size_t)sn * 128 + c4);
  };

  int idx[4];
  uint2 pv[4];
  #pragma unroll
  for (int k = 0; k < 4; ++k) idx[k] = colidx[eclamp(k)];
  #pragma unroll
  for (int k = 0; k < 4; ++k) pv[k] = ldx(idx[k]);
  for (int i = 0; i < nstep; i += 4) {
    uint2 q[4];
    #pragma unroll
    for (int k = 0; k < 4; ++k) q[k] = pv[k];
    if (i + 4 < nstep) {
      #pragma unroll
      for (int k = 0; k < 4; ++k) idx[k] = colidx[eclamp(i + 4 + k)];
      #pragma unroll
      for (int k = 0; k < 4; ++k) pv[k] = ldx(idx[k]);
    }
    step(q[0], 2 * i + half < cnt);
    if (i + 1 < nstep) step(q[1], 2 * (i + 1) + half < cnt);
    if (i + 2 < nstep) step(q[2], 2 * (i + 2) + half < cnt);
    if (i + 3 < nstep) step(q[3], 2 * (i + 3) + half < cnt);
  }

  // merge the two half-wave softmax states (lane l <-> l^32 hold same channels).
  // empty half (cnt==1) has m_=-1e30 -> its weight exp(m_-nm)=0 kills any junk.
  float om = __shfl_xor(m_, 32, 64);
  float os = __shfl_xor(s_, 32, 64);
  float oa0 = __shfl_xor(ac0, 32, 64);
  float oa1 = __shfl_xor(ac1, 32, 64);
  float oa2 = __shfl_xor(ac2, 32, 64);
  float oa3 = __shfl_xor(ac3, 32, 64);
  float nm = fmaxf(m_, om);
  float ps = __expf(m_ - nm), po = __expf(om - nm);
  float s = s_ * ps + os * po;
  float inv = 1.f / (s + 1e-16f);
  float4 cbv = *reinterpret_cast<const float4*>(cb + c4);
  float v0 = (ac0 * ps + oa0 * po) * inv + cbv.x;
  float v1 = (ac1 * ps + oa1 * po) * inv + cbv.y;
  float v2 = (ac2 * ps + oa2 * po) * inv + cbv.z;
  float v3 = (ac3 * ps + oa3 * po) * inv + cbv.w;
  if (RES) {
    uint2 rv = *reinterpret_cast<const uint2*>(res + base + c4);
    v0 += bf2f(rv.x & 0xffffu); v1 += bf2f(rv.x >> 16);
    v2 += bf2f(rv.y & 0xffffu); v3 += bf2f(rv.y >> 16);
  }
  float S = v0 + v1 + v2 + v3;
  float Q = v0 * v0 + v1 * v1 + v2 * v2 + v3 * v3;
  #pragma unroll
  for (int m = 16; m >= 1; m >>= 1) {
    S += __shfl_xor(S, m, 64);
    Q += __shfl_xor(Q, m, 64);
  }
  float mean = S * (1.f / 128.f);
  float var = Q * (1.f / 128.f) - mean * mean;
  float rstd = rsqrtf(var + 1e-5f);
  float4 gv = *reinterpret_cast<const float4*>(g + c4);
  float4 bv = *reinterpret_cast<const float4*>(b + c4);
  float y0 = (v0 - mean) * rstd * gv.x + bv.x;
  float y1 = (v1 - mean) * rstd * gv.y + bv.y;
  float y2 = (v2 - mean) * rstd * gv.z + bv.z;
  float y3 = (v3 - mean) * rstd * gv.w + bv.w;
  y0 = (y0 > 0.f) ? y0 : expm1f(y0);
  y1 = (y1 > 0.f) ? y1 : expm1f(y1);
  y2 = (y2 > 0.f) ? y2 : expm1f(y2);
  y3 = (y3 > 0.f) ? y3 : expm1f(y3);
  if (half == 0) {   // both halves hold identical merged results; one stores
    uint2 o;
    o.x = (unsigned int)f2bf(y0) | ((unsigned int)f2bf(y1) << 16);
    o.y = (unsigned int)f2bf(y2) | ((unsigned int)f2bf(y3) << 16);
    *reinterpret_cast<uint2*>(out + base + c4) = o;
  }
}

// ================== kernels ==================

// L1: init (cnt=1, fill=1, marks=0, cnts=0, scan aggs=0) || weight pack
__global__ __launch_bounds__(256) void k_initpack(
    int* cnt, int* fill, int* m3, int* m2, int* cnts, int* agg,
    const float* __restrict__ W0l, const float* __restrict__ W0r, unsigned short* o0,
    const float* __restrict__ W1l, const float* __restrict__ W1r, unsigned short* o1,
    const float* __restrict__ W2l, const float* __restrict__ W2r, unsigned short* o2,
    const float* __restrict__ W3l, const float* __restrict__ W3r, unsigned short* o3,
    const float* __restrict__ Wt, unsigned short* ot,
    const float* __restrict__ Wv, unsigned short* ov,
    const float* __restrict__ Wa, unsigned short* oa) {
  int bid = blockIdx.x;
  if (bid < NBLK_N) {
    int i = bid * 256 + threadIdx.x;
    if (i < NND) { cnt[i] = 1; fill[i] = 1; m3[i] = 0; m2[i] = 0; }
    if (i < 2) cnts[i] = 0;
    if (i < 128) agg[i] = 0;
    return;
  }
  pack_body((bid - NBLK_N) * 256 + threadIdx.x,
            W0l, W0r, o0, W1l, W1r, o1, W2l, W2r, o2, W3l, W3r, o3,
            Wt, ot, Wv, ov, Wa, oa);
}

// L2: all three input projections (split-K x2) || degree count
__global__ __launch_bounds__(256) void k_gin_count(
    const float* __restrict__ x, const unsigned short* __restrict__ wbt,
    const float* __restrict__ bt, unsigned short* fx, float* rowmean,
    const float* __restrict__ xv, const unsigned short* __restrict__ wbv,
    const float* __restrict__ bv, float* hvraw,
    const float* __restrict__ xa, const unsigned short* __restrict__ wba,
    const float* __restrict__ ba, float* haraw,
    const int* __restrict__ dst, int* cnt) {
  __shared__ float lred[2 * 64 * 9];
  int bid = blockIdx.x;
  if (bid < NTB_TXT) {
    gemm_in_body<TDIM, true, true>(x, wbt, bt, fx, rowmean, bid, lred);
    return;
  }
  bid -= NTB_TXT;
  if (bid < NTB_VIS) {
    gemm_in_body<VDIM, false, false>(xv, wbv, bv, hvraw, nullptr, bid, lred);
    return;
  }
  bid -= NTB_VIS;
  if (bid < NTB_AUD) {
    gemm_in_body<ADIM, false, false>(xa, wba, ba, haraw, nullptr, bid, lred);
    return;
  }
  bid -= NTB_AUD;
  int i = bid * 256 + threadIdx.x;
  if (i < NED) atomicAdd(&cnt[dst[i]], 1);
}

// L3: rowptr scan (decoupled lookback; scan blocks FIRST for co-residency) || modal
__global__ __launch_bounds__(256) void k_scan_modal(
    const int* __restrict__ cnt, int* rp, int* agg,
    unsigned short* fx, const float* __restrict__ hv, const float* __restrict__ ha,
    const int* __restrict__ vidx, const int* __restrict__ aidx,
    const float* __restrict__ gv, const float* __restrict__ bev,
    const float* __restrict__ ga, const float* __restrict__ bea,
    const float* __restrict__ rowmean) {
  __shared__ int lds[256];
  int bid = blockIdx.x;
  if (bid < NSCAN) {
    scan_body(cnt, rp, agg, NND, bid, lds);
    return;
  }
  modal_body(fx, hv, ha, vidx, aidx, gv, bev, ga, bea, rowmean, NVV, NAA, bid - NSCAN);
}

// L4 (512 thr): layer-1 projection || CSR fill (self-loop + edges)
__global__ __launch_bounds__(512) void k_fill_gemm1(
    const unsigned short* __restrict__ fx, const unsigned short* __restrict__ wb0,
    const float* __restrict__ bl, const float* __restrict__ br,
    unsigned short* __restrict__ xlb, unsigned short* __restrict__ xrb,
    const int* __restrict__ src, const int* __restrict__ dst,
    const int* __restrict__ rp, int* fill, int* colidx) {
  int bid = blockIdx.x;
  if (bid < NTILE) {
    gemm_body<32, 128, 8, 0>(fx, wb0, bl, br, xlb, xrb, NND, nullptr, nullptr, bid);
    return;
  }
  int i = (bid - NTILE) * 512 + threadIdx.x;
  if (i < NND) colidx[rp[i]] = i;                 // self-loop in slot 0
  if (i < NED) {
    int d = dst[i];
    int p = atomicAdd(&fill[d], 1);               // p >= 1
    colidx[rp[d] + p] = src[i];
  }
}

// L5: layer-1 aggregation (full) || layer-4 prep + S3 mark
__global__ __launch_bounds__(256) void k_agg1_prep(
    const unsigned short* __restrict__ xlb, const unsigned short* __restrict__ xrb,
    const float* __restrict__ att, const int* __restrict__ rp,
    const int* __restrict__ colidx, const float* __restrict__ cb,
    const float* __restrict__ g, const float* __restrict__ b,
    unsigned short* __restrict__ h,
    const int* __restrict__ ptr, int* off, int* gidx, int* mark3) {
  __shared__ int cnt_s[64];
  __shared__ int off_s[65];
  int bid = blockIdx.x;
  if (bid < NWAVEN / 4 * 4 / 4) {}  // (no-op; keep structure readable)
  if (bid < 25000) {
    agg_body<false, false>(xlb, xrb, att, rp, colidx, cb, nullptr, g, b, h, NND,
                           nullptr, nullptr, bid);
    return;
  }
  prep4_body(ptr, rp, colidx, off, gidx, mark3, bid - 25000, cnt_s, off_s);
}

// L6 (512 thr): layer-2 projection || S2 mark || compact S3 -> list3
__global__ __launch_bounds__(512) void k_gemm2_mark(
    const unsigned short* __restrict__ h, const unsigned short* __restrict__ wb1,
    const float* __restrict__ bl, const float* __restrict__ br,
    unsigned short* __restrict__ xlb, unsigned short* __restrict__ xrb,
    const int* __restrict__ mark3, int* mark2,
    const int* __restrict__ rp, const int* __restrict__ colidx,
    int* list3, int* cnts) {
  int bid = blockIdx.x;
  if (bid < NTILE) {
    gemm_body<128, 128, 8, 0>(h, wb1, bl, br, xlb, xrb, NND, nullptr, nullptr, bid);
    return;
  }
  bid -= NTILE;
  if (bid < NM512) {   // S2 mark
    int i = bid * 512 + threadIdx.x;
    if (i < NND && mark3[i]) {
      mark2[i] = 1;
      int eb = rp[i], ee = rp[i + 1];
      for (int e = eb; e < ee; ++e) mark2[colidx[e]] = 1;
    }
    return;
  }
  bid -= NM512;        // compact S3 -> list3
  int i = bid * 512 + threadIdx.x;
  if (i < NND && mark3[i]) { int p = atomicAdd(&cnts[0], 1); list3[p] = i; }
}

// L7: compact S2 -> list2
__global__ __launch_bounds__(256) void k_compact1(
    const int* __restrict__ m2, int* l2, int* cnt, int n) {
  int i = blockIdx.x * 256 + threadIdx.x;
  if (i < n && m2[i]) { int p = atomicAdd(cnt, 1); l2[p] = i; }
}

// standalone wrappers
template <int K, int NHALF, int WAVES, int MODE>
__global__ __launch_bounds__(WAVES * 64) void gemm_mfma(
    const unsigned short* __restrict__ A, const unsigned short* __restrict__ Wb,
    const float* __restrict__ bl, const float* __restrict__ br,
    unsigned short* __restrict__ Cl, unsigned short* __restrict__ Cr, int M,
    const int* __restrict__ rows, const int* __restrict__ rcnt) {
  gemm_body<K, NHALF, WAVES, MODE>(A, Wb, bl, br, Cl, Cr, M, rows, rcnt, blockIdx.x);
}

template <bool RES, bool WL>
__global__ __launch_bounds__(256) void gat_agg_post128(
    const unsigned short* __restrict__ xl, const unsigned short* __restrict__ xr,
    const float* __restrict__ att, const int* __restrict__ rp,
    const int* __restrict__ colidx, const float* __restrict__ cb,
    const unsigned short* res, const float* __restrict__ g,
    const float* __restrict__ b, unsigned short* __restrict__ out, int n,
    const int* __restrict__ wl, const int* __restrict__ wcnt) {
  agg_body<RES, WL>(xl, xr, att, rp, colidx, cb, res, g, b, out, n, wl, wcnt, blockIdx.x);
}

// fused layer-4 agg + LN + Wo dot. 4 nodes/wave (16-lane groups), 64 nodes total.
__global__ __launch_bounds__(256) void k_agg4_final(
    const unsigned short* __restrict__ xls, const unsigned short* __restrict__ xrs,
    const float* __restrict__ att, const int* __restrict__ off,
    const float* __restrict__ cb, const float* __restrict__ g,
    const float* __restrict__ b, const float* __restrict__ Wo,
    const float* __restrict__ bo, float* __restrict__ out) {
  int wid = (blockIdx.x * 256 + threadIdx.x) >> 6;  // 0..15
  int l = threadIdx.x & 63;
  int lg = l & 15;
  int node = 4 * wid + (l >> 4);  // 0..63
  int c2 = 2 * lg;
  int p0 = off[node], pe = off[node + 1];
  int deg = pe - p0 - 1;  // >= 1 (self-loop)
  float2 a = *reinterpret_cast<const float2*>(att + c2);
  unsigned int xru = *reinterpret_cast<const unsigned int*>(xrs + (size_t)p0 * 32 + c2);
  float xr0 = bf2f(xru & 0xffffu), xr1 = bf2f(xru >> 16);
  float m_ = -1e30f, s_ = 0.f, accx = 0.f, accy = 0.f;
  for (int i = 0;; ++i) {
    bool go = i < deg;
    if (!__any(go)) break;
    float xcx = 0.f, xcy = 0.f;
    float t = -1e30f;
    if (go) {
      unsigned int pv = *reinterpret_cast<const unsigned int*>(xls + (size_t)(p0 + 1 + i) * 32 + c2);
      xcx = bf2f(pv & 0xffffu);
      xcy = bf2f(pv >> 16);
      float z0 = xcx + xr0, z1 = xcy + xr1;
      t = (z0 > 0.f ? z0 : 0.2f * z0) * a.x + (z1 > 0.f ? z1 : 0.2f * z1) * a.y;
    }
    t = red16(t);
    if (!go) t = -1e30f;
    if (__any(t > m_ + 4.0f)) {
      float nm = fmaxf(m_, t);
      float p = __expf(m_ - nm);
      float w = __expf(t - nm);
      s_ = s_ * p + w;
      accx = accx * p + w * xcx;
      accy = accy * p + w * xcy;
      m_ = nm;
    } else {
      float w = __expf(t - m_);
      s_ += w;
      accx = fmaf(w, xcx, accx);
      accy = fmaf(w, xcy, accy);
    }
  }
  float inv = 1.f / (s_ + 1e-16f);
  float2 cbv = *reinterpret_cast<const float2*>(cb + c2);
  float v0 = accx * inv + cbv.x;
  float v1 = accy * inv + cbv.y;
  float S = red16(v0 + v1);
  float Q = red16(v0 * v0 + v1 * v1);
  float mean = S * (1.f / 32.f);
  float var = Q * (1.f / 32.f) - mean * mean;
  float rstd = rsqrtf(var + 1e-5f);
  float2 gv = *reinterpret_cast<const float2*>(g + c2);
  float2 bv = *reinterpret_cast<const float2*>(b + c2);
  float y0 = (v0 - mean) * rstd * gv.x + bv.x;
  float y1 = (v1 - mean) * rstd * gv.y + bv.y;
  float2 wo = *reinterpret_cast<const float2*>(Wo + c2);
  float d = red16(y0 * wo.x + y1 * wo.y);
  if (lg == 0) out[node] = d + bo[0];
}

// ---------------- host ----------------
extern "C" void kernel_launch(void* const* d_in, const int* in_sizes, int n_in,
                              void* d_out, int out_size, void* d_ws, size_t ws_size,
                              hipStream_t stream) {
  const float* x   = (const float*)d_in[0];
  const float* xv  = (const float*)d_in[1];
  const float* xa  = (const float*)d_in[2];
  const int* src   = (const int*)d_in[3];
  const int* dst   = (const int*)d_in[4];
  const int* vidx  = (const int*)d_in[5];
  const int* aidx  = (const int*)d_in[6];
  const int* ptr   = (const int*)d_in[7];
  const float* Wt  = (const float*)d_in[8];
  const float* bt  = (const float*)d_in[9];
  const float* Wv  = (const float*)d_in[10];
  const float* bv  = (const float*)d_in[11];
  const float* gv  = (const float*)d_in[12];
  const float* bev = (const float*)d_in[13];
  const float* Wa  = (const float*)d_in[14];
  const float* ba  = (const float*)d_in[15];
  const float* ga  = (const float*)d_in[16];
  const float* bea = (const float*)d_in[17];
  const float* cW_l[4], *cb_l[4], *cW_r[4], *cb_r[4], *c_att[4], *c_b[4];
  for (int i = 0; i < 4; ++i) {
    cW_l[i]  = (const float*)d_in[18 + 6 * i + 0];
    cb_l[i]  = (const float*)d_in[18 + 6 * i + 1];
    cW_r[i]  = (const float*)d_in[18 + 6 * i + 2];
    cb_r[i]  = (const float*)d_in[18 + 6 * i + 3];
    c_att[i] = (const float*)d_in[18 + 6 * i + 4];
    c_b[i]   = (const float*)d_in[18 + 6 * i + 5];
  }
  const float* ng[4], *nb_[4];
  for (int i = 0; i < 4; ++i) {
    ng[i]  = (const float*)d_in[42 + 2 * i + 0];
    nb_[i] = (const float*)d_in[42 + 2 * i + 1];
  }
  const float* Wo = (const float*)d_in[50];
  const float* bo = (const float*)d_in[51];
  float* out = (float*)d_out;

  char* w = (char*)d_ws;
  auto alloc = [&](size_t bytes) {
    char* p = w;
    w += (bytes + 255) & ~(size_t)255;
    return p;
  };
  int* rowptr = (int*)alloc((NND + 1) * sizeof(int));
  int* cnt    = (int*)alloc(NND * sizeof(int));
  int* aggs   = (int*)alloc(128 * sizeof(int));
  int* colidx = (int*)alloc((size_t)(NED + NND) * sizeof(int));
  float* rowmean = (float*)alloc((size_t)NND * sizeof(float));
  unsigned short* fx = (unsigned short*)alloc((size_t)NND * 32 * sizeof(unsigned short));
  unsigned short* h  = (unsigned short*)alloc((size_t)NND * 128 * sizeof(unsigned short));
  unsigned short* xlb = (unsigned short*)alloc((size_t)NND * 128 * sizeof(unsigned short));
  unsigned short* xrb = (unsigned short*)alloc((size_t)NND * 128 * sizeof(unsigned short));
  float* hvraw = (float*)alloc((size_t)NVV * 32 * sizeof(float));
  float* haraw = (float*)alloc((size_t)NAA * 32 * sizeof(float));
  unsigned short* wb0 = (unsigned short*)alloc(256 * 32 * sizeof(unsigned short));
  unsigned short* wb1 = (unsigned short*)alloc(256 * 128 * sizeof(unsigned short));
  unsigned short* wb2 = (unsigned short*)alloc(256 * 128 * sizeof(unsigned short));
  unsigned short* wb3 = (unsigned short*)alloc(64 * 128 * sizeof(unsigned short));
  unsigned short* wbt = (unsigned short*)alloc(32 * TDIM * sizeof(unsigned short));
  unsigned short* wbv = (unsigned short*)alloc(32 * VDIM * sizeof(unsigned short));
  unsigned short* wba = (unsigned short*)alloc(32 * ADIM * sizeof(unsigned short));
  int* off4 = (int*)alloc(65 * sizeof(int));
  int* gidx = (int*)alloc(SUBROWS * sizeof(int));
  unsigned short* xls = (unsigned short*)alloc((size_t)SUBROWS * 32 * sizeof(unsigned short));
  unsigned short* xrs = (unsigned short*)alloc((size_t)SUBROWS * 32 * sizeof(unsigned short));
  int* mark3 = (int*)alloc((size_t)NND * sizeof(int));
  int* mark2 = (int*)alloc((size_t)NND * sizeof(int));
  int* list3 = (int*)alloc((size_t)NND * sizeof(int));
  int* list2 = (int*)alloc((size_t)NND * sizeof(int));
  int* cnts  = (int*)alloc(2 * sizeof(int));

  // fill (edge-fill cursor) reuses list2's space: list2 written only by k_compact1,
  // which runs after k_fill_gemm1 completes.
  int* fill = list2;

  // L1: init || pack
  k_initpack<<<NBLK_N + NPACK, 256, 0, stream>>>(
      cnt, fill, mark3, mark2, cnts, aggs,
      cW_l[0], cW_r[0], wb0, cW_l[1], cW_r[1], wb1,
      cW_l[2], cW_r[2], wb2, cW_l[3], cW_r[3], wb3,
      Wt, wbt, Wv, wbv, Wa, wba);
  // L2: input projections || degree count
  k_gin_count<<<NTB_TXT + NTB_VIS + NTB_AUD + NBLK_E, 256, 0, stream>>>(
      x, wbt, bt, fx, rowmean, xv, wbv, bv, hvraw, xa, wba, ba, haraw, dst, cnt);
  // L3: scan || modal overwrite
  k_scan_modal<<<NSCAN + NWAVEM2, 256, 0, stream>>>(
      cnt, rowptr, aggs, fx, hvraw, haraw, vidx, aidx, gv, bev, ga, bea, rowmean);
  // L4: layer-1 projection || CSR fill
  k_fill_gemm1<<<NTILE + NBLK_E512, 512, 0, stream>>>(
      fx, wb0, cb_l[0], cb_r[0], xlb, xrb, src, dst, rowptr, fill, colidx);
  // L5: layer-1 aggregation || layer-4 prep + S3 mark
  k_agg1_prep<<<25000 + 65, 256, 0, stream>>>(
      xlb, xrb, c_att[0], rowptr, colidx, c_b[0], ng[0], nb_[0], h,
      ptr, off4, gidx, mark3);
  // L6: layer-2 projection || S2 mark || compact3
  k_gemm2_mark<<<NTILE + NM512 + NM512, 512, 0, stream>>>(
      h, wb1, cb_l[1], cb_r[1], xlb, xrb, mark3, mark2, rowptr, colidx, list3, cnts);
  // L7: compact S2 -> list2
  k_compact1<<<NBLK_N, 256, 0, stream>>>(mark2, list2, cnts + 1, NND);
  // L8: layer-2 aggregation (S2 only)
  gat_agg_post128<true, true><<<NWAVEN, 256, 0, stream>>>(
      xlb, xrb, c_att[1], rowptr, colidx, c_b[1], h, ng[1], nb_[1], h, NND,
      list2, cnts + 1);
  // L9: layer-3 projection (S2 rows only, gather/scatter)
  gemm_mfma<128, 128, 8, 1><<<NTILE, 512, 0, stream>>>(
      h, wb2, cb_l[2], cb_r[2], xlb, xrb, NND, list2, cnts + 1);
  // L10: layer-3 aggregation (S3 only)
  gat_agg_post128<true, true><<<4096, 256, 0, stream>>>(
      xlb, xrb, c_att[2], rowptr, colidx, c_b[2], h, ng[2], nb_[2], h, NND,
      list3, cnts + 0);
  // L11: layer-4 projection (gather h rows via gidx, linear out)
  gemm_mfma<128, 32, 4, 2><<<SUBROWS / 16, 256, 0, stream>>>(
      h, wb3, cb_l[3], cb_r[3], xls, xrs, SUBROWS, gidx, off4 + 64);
  // L12: final agg + LN + Wo
  k_agg4_final<<<4, 256, 0, stream>>>(
      xls, xrs, c_att[3], off4, c_b[3], ng[3], nb_[3], Wo, bo, out);
}